// Round 1
// baseline (7756.313 us; speedup 1.0000x reference)
//
#include <hip/hip_runtime.h>
#include <stdint.h>

// Problem constants (fixed by the reference): B=2048, S=512, F=64, H=256
#define SEQ   512
#define FD    64
#define HD    256
#define KD    320            // F + H
#define ZSTR  328            // padded bf16 row stride for Z [16][320] (stride%32 words = 4)
#define CSTR  264            // padded bf16 row stride for CB [16][256]

typedef __attribute__((ext_vector_type(8))) __bf16 bf16x8;
typedef __attribute__((ext_vector_type(4))) float  f32x4;

__device__ __forceinline__ float sigm(float x) {
    // 1/(1+e^-x); v_exp + v_rcp. Large |x| saturates correctly (inf -> 0).
    return __builtin_amdgcn_rcpf(1.0f + __expf(-x));
}
__device__ __forceinline__ float tanh_(float x) {
    // 2*sigmoid(2x)-1; for x -> +inf: exp(-2x)->0 -> 1; x -> -inf: rcp(inf)=0 -> -1.
    return 2.0f * __builtin_amdgcn_rcpf(1.0f + __expf(-2.0f * x)) - 1.0f;
}

// One block = 16 batch rows for the entire 512-step sequence.
// 16 waves; wave w owns hidden slice j in [16w, 16w+16) for ALL FOUR gates.
// Gate weights live in VGPRs for the whole kernel (160 VGPRs/lane).
__global__ __launch_bounds__(1024) void lstm_persist(
    const float* __restrict__ h0,
    const float* __restrict__ c0,
    const float* __restrict__ W_ih,     // [1024][64]
    const float* __restrict__ W_hh,     // [1024][256]
    const float* __restrict__ b_ih,     // [1024]
    const float* __restrict__ b_hh,     // [1024]
    const float* __restrict__ W_dense,  // [64][256]
    const float* __restrict__ b_dense,  // [64]
    float* __restrict__ out)            // [2048][512][64]
{
    __shared__ __align__(16) __bf16 Zb[2 * 16 * ZSTR]; // [x(64) | h(256)] bf16, double buffered
    __shared__ __align__(16) __bf16 CB[16 * CSTR];     // c_new bf16 (A-operand for dense)

    const int tid = threadIdx.x;
    const int w   = tid >> 6;     // wave 0..15
    const int l   = tid & 63;
    const int lr  = l & 15;       // low lane bits: A-row / B-col / D-col
    const int lg  = l >> 4;       // lane group 0..3: k-group / D-row-group
    const int row0 = blockIdx.x * 16;

    const int j = w * 16 + lr;    // hidden unit owned by this lane

    // ---------------- register-resident weights ----------------
    // B-frag element e <-> k = ks*32 + lg*8 + e (consistent bijection used for A too)
    bf16x8 wg[4][10];             // [gate nt][ks]
    float  biasr[4];
#pragma unroll
    for (int nt = 0; nt < 4; ++nt) {
        const int n = nt * 256 + j;                 // row of W_ih/W_hh
        biasr[nt] = b_ih[n] + b_hh[n];
#pragma unroll
        for (int ks = 0; ks < 10; ++ks) {
            const int k0 = ks * 32 + lg * 8;        // ks<2 -> x-part, else h-part
            const float* src = (k0 < 64) ? (W_ih + n * 64 + k0)
                                         : (W_hh + n * 256 + (k0 - 64));
            bf16x8 v;
#pragma unroll
            for (int e = 0; e < 8; ++e) v[e] = (__bf16)src[e];
            wg[nt][ks] = v;
        }
    }

    // dense weights (waves 0..3 compute y = c_new @ W_dense^T + b_dense)
    bf16x8 wd[8];
    float  ybias = 0.0f;
    if (w < 4) {
        const int f = w * 16 + lr;
        ybias = b_dense[f];
#pragma unroll
        for (int ks = 0; ks < 8; ++ks) {
            const int k0 = ks * 32 + lg * 8;
            const float* src = W_dense + f * 256 + k0;
            bf16x8 v;
#pragma unroll
            for (int e = 0; e < 8; ++e) v[e] = (__bf16)src[e];
            wd[ks] = v;
        }
    }

    // ---------------- initial state ----------------
    // c in registers, D-fragment layout: rows m = lg*4+r, col j
    float creg[4];
#pragma unroll
    for (int r = 0; r < 4; ++r)
        creg[r] = c0[(size_t)(row0 + lg * 4 + r) * HD + j];

    // stage h0 -> Z0 h-part (bf16); 4096 elems, 4 consecutive per thread
    {
        const int e0 = tid * 4;
        const int m  = e0 >> 8;
        const int jj = e0 & 255;
        const float4 hv = *(const float4*)(h0 + (size_t)(row0 + m) * HD + jj);
        __bf16* zp = &Zb[m * ZSTR + 64 + jj];
        zp[0] = (__bf16)hv.x; zp[1] = (__bf16)hv.y;
        zp[2] = (__bf16)hv.z; zp[3] = (__bf16)hv.w;
    }
    __syncthreads();

    // x_0 = dense(h0): waves 0..3, A-frags read from Z0 h-part, write Z0 x-part
    if (w < 4) {
        f32x4 ya = {ybias, ybias, ybias, ybias};
#pragma unroll
        for (int ks = 0; ks < 8; ++ks) {
            bf16x8 a = *(const bf16x8*)(&Zb[lr * ZSTR + 64 + ks * 32 + lg * 8]);
            ya = __builtin_amdgcn_mfma_f32_16x16x32_bf16(a, wd[ks], ya, 0, 0, 0);
        }
        const int f = w * 16 + lr;
#pragma unroll
        for (int r = 0; r < 4; ++r)
            Zb[(lg * 4 + r) * ZSTR + f] = (__bf16)ya[r];
    }

    float* outp = out + (size_t)row0 * SEQ * FD;

    // ---------------- 512-step recurrence ----------------
    for (int t = 0; t < SEQ; ++t) {
        __syncthreads();  // Z[cur] complete (h + x from previous iteration)

        const __bf16* Zc = &Zb[(t & 1) * (16 * ZSTR)];
        __bf16*       Zn = &Zb[((t + 1) & 1) * (16 * ZSTR)];

        // A-frags: lane holds Z[row lr][k = ks*32 + lg*8 + e] — one ds_read_b128 each
        bf16x8 a[10];
#pragma unroll
        for (int ks = 0; ks < 10; ++ks)
            a[ks] = *(const bf16x8*)(&Zc[lr * ZSTR + ks * 32 + lg * 8]);

        // gates: 4 independent accumulator chains (i, f, g, o) for hidden j
        f32x4 acc[4];
#pragma unroll
        for (int nt = 0; nt < 4; ++nt) {
            f32x4 c4 = {biasr[nt], biasr[nt], biasr[nt], biasr[nt]};
#pragma unroll
            for (int ks = 0; ks < 10; ++ks)
                c4 = __builtin_amdgcn_mfma_f32_16x16x32_bf16(a[ks], wg[nt][ks], c4, 0, 0, 0);
            acc[nt] = c4;
        }

        // element-wise LSTM update; (m, j) owned by this lane for r = 0..3
#pragma unroll
        for (int r = 0; r < 4; ++r) {
            const int m = lg * 4 + r;
            const float ig = sigm(acc[0][r]);
            const float fg = sigm(acc[1][r]);
            const float gg = tanh_(acc[2][r]);
            const float og = sigm(acc[3][r]);
            const float cn = fg * creg[r] + ig * gg;
            creg[r] = cn;                         // fp32 master state stays in regs
            const float hn = og * tanh_(cn);
            Zn[m * ZSTR + 64 + j] = (__bf16)hn;   // h for next step
            CB[m * CSTR + j]      = (__bf16)cn;   // A-operand for dense
        }

        __syncthreads();  // CB ready (and prev CB readers are past the top barrier)

        // y_t = c_new @ W_dense^T + b_dense  (waves 0..3; 8 MFMAs)
        if (w < 4) {
            f32x4 ya = {ybias, ybias, ybias, ybias};
#pragma unroll
            for (int ks = 0; ks < 8; ++ks) {
                bf16x8 av = *(const bf16x8*)(&CB[lr * CSTR + ks * 32 + lg * 8]);
                ya = __builtin_amdgcn_mfma_f32_16x16x32_bf16(av, wd[ks], ya, 0, 0, 0);
            }
            const int f = w * 16 + lr;
#pragma unroll
            for (int r = 0; r < 4; ++r) {
                const int m = lg * 4 + r;
                outp[(size_t)m * SEQ * FD + (size_t)t * FD + f] = ya[r]; // output (fp32)
                Zn[m * ZSTR + f] = (__bf16)ya[r];                        // x for next step
            }
        }
    }
}

extern "C" void kernel_launch(void* const* d_in, const int* in_sizes, int n_in,
                              void* d_out, int out_size, void* d_ws, size_t ws_size,
                              hipStream_t stream) {
    (void)in_sizes; (void)n_in; (void)d_ws; (void)ws_size; (void)out_size;
    // setup_inputs order: x(0, unused), h0(1), c0(2), W_ih(3), W_hh(4),
    //                     b_ih(5), b_hh(6), W_dense(7), b_dense(8), seq_len(9)
    const float* h0      = (const float*)d_in[1];
    const float* c0      = (const float*)d_in[2];
    const float* W_ih    = (const float*)d_in[3];
    const float* W_hh    = (const float*)d_in[4];
    const float* b_ih    = (const float*)d_in[5];
    const float* b_hh    = (const float*)d_in[6];
    const float* W_dense = (const float*)d_in[7];
    const float* b_dense = (const float*)d_in[8];

    lstm_persist<<<128, 1024, 0, stream>>>(h0, c0, W_ih, W_hh, b_ih, b_hh,
                                           W_dense, b_dense, (float*)d_out);
}

// Round 2
// 7463.808 us; speedup vs baseline: 1.0392x; 1.0392x over previous
//
#include <hip/hip_runtime.h>
#include <stdint.h>

// Problem constants (fixed by the reference): B=2048, S=512, F=64, H=256
#define SEQ   512
#define FD    64
#define HD    256
#define KD    320            // F + H
// LDS strides chosen so stride_words % 8 == 2:
//  - b128 A-frag reads: bank = (2*lr + 4*lg) % 32 -> uniform 8 accesses/bank (floor)
//  - scalar bf16 row writes (m = lg*4+r): 4*lg*stride spreads {0,8,16,24} -> <=2-way
#define ZSTR  324            // bf16 elems per Z row (>=320); 162 words, 162%8==2
#define CSTR  260            // bf16 elems per CB row (>=256); 130 words, 130%8==2

typedef __attribute__((ext_vector_type(8))) __bf16 bf16x8;
typedef __attribute__((ext_vector_type(4))) float  f32x4;

__device__ __forceinline__ float sigm(float x) {
    // 1/(1+e^-x); v_exp + v_rcp. Large |x| saturates correctly (inf -> 0).
    return __builtin_amdgcn_rcpf(1.0f + __expf(-x));
}
__device__ __forceinline__ float tanh_(float x) {
    // 2*sigmoid(2x)-1; x -> +inf: exp -> 0 -> 1; x -> -inf: rcp(inf) = 0 -> -1.
    return 2.0f * __builtin_amdgcn_rcpf(1.0f + __expf(-2.0f * x)) - 1.0f;
}

// One block = 16 batch rows for the entire 512-step sequence.
// 16 waves; wave w owns hidden slice j in [16w, 16w+16) for ALL FOUR gates.
// Gate weights live in VGPRs for the whole kernel (160 VGPRs/lane).
// __launch_bounds__(1024, 4): 16-wave block = 4 waves/SIMD minimum -> VGPR cap 512.
__global__ __launch_bounds__(1024, 4) void lstm_persist(
    const float* __restrict__ h0,
    const float* __restrict__ c0,
    const float* __restrict__ W_ih,     // [1024][64]
    const float* __restrict__ W_hh,     // [1024][256]
    const float* __restrict__ b_ih,     // [1024]
    const float* __restrict__ b_hh,     // [1024]
    const float* __restrict__ W_dense,  // [64][256]
    const float* __restrict__ b_dense,  // [64]
    float* __restrict__ out)            // [2048][512][64]
{
    __shared__ __align__(16) __bf16 Zb[2 * 16 * ZSTR]; // [x(64) | h(256)] bf16, dbuf
    __shared__ __align__(16) __bf16 CB[16 * CSTR];     // c_new bf16 (A-operand for dense)

    const int tid = threadIdx.x;
    const int w   = tid >> 6;     // wave 0..15
    const int l   = tid & 63;
    const int lr  = l & 15;       // A-row / B-col / D-col
    const int lg  = l >> 4;       // lane group 0..3: k-group / D-row-group
    const int row0 = blockIdx.x * 16;

    const int j = w * 16 + lr;    // hidden unit owned by this lane

    // ---------------- register-resident weights ----------------
    // frag element e <-> k = ks*32 + lg*8 + e (same bijection for A and B)
    bf16x8 wg[4][10];             // [gate nt][ks]  -- 160 VGPRs
    float  biasr[4];
#pragma unroll
    for (int nt = 0; nt < 4; ++nt) {
        const int n = nt * 256 + j;                 // row of W_ih/W_hh
        biasr[nt] = b_ih[n] + b_hh[n];
#pragma unroll
        for (int ks = 0; ks < 10; ++ks) {
            const int k0 = ks * 32 + lg * 8;        // ks<2 -> x-part, else h-part
            const float* src = (k0 < 64) ? (W_ih + n * 64 + k0)
                                         : (W_hh + n * 256 + (k0 - 64));
            bf16x8 v;
#pragma unroll
            for (int e = 0; e < 8; ++e) v[e] = (__bf16)src[e];
            wg[nt][ks] = v;
        }
    }

    // dense weights (waves 0..3 compute y = c_new @ W_dense^T + b_dense)
    bf16x8 wd[8];
    float  ybias = 0.0f;
    if (w < 4) {
        const int f = w * 16 + lr;
        ybias = b_dense[f];
#pragma unroll
        for (int ks = 0; ks < 8; ++ks) {
            const int k0 = ks * 32 + lg * 8;
            const float* src = W_dense + f * 256 + k0;
            bf16x8 v;
#pragma unroll
            for (int e = 0; e < 8; ++e) v[e] = (__bf16)src[e];
            wd[ks] = v;
        }
    }

    // ---------------- initial state ----------------
    // c in registers, D-fragment layout: rows m = lg*4+r, col j
    float creg[4];
#pragma unroll
    for (int r = 0; r < 4; ++r)
        creg[r] = c0[(size_t)(row0 + lg * 4 + r) * HD + j];

    // stage h0 -> Z0 h-part (bf16); 4096 elems, 4 consecutive per thread
    {
        const int e0 = tid * 4;
        const int m  = e0 >> 8;
        const int jj = e0 & 255;
        const float4 hv = *(const float4*)(h0 + (size_t)(row0 + m) * HD + jj);
        __bf16* zp = &Zb[m * ZSTR + 64 + jj];
        zp[0] = (__bf16)hv.x; zp[1] = (__bf16)hv.y;
        zp[2] = (__bf16)hv.z; zp[3] = (__bf16)hv.w;
    }
    __syncthreads();

    // x_0 = dense(h0): waves 0..3, A-frags from Z0 h-part, write Z0 x-part
    if (w < 4) {
        f32x4 ya = {ybias, ybias, ybias, ybias};
#pragma unroll
        for (int ks = 0; ks < 8; ++ks) {
            bf16x8 a = *(const bf16x8*)(&Zb[lr * ZSTR + 64 + ks * 32 + lg * 8]);
            ya = __builtin_amdgcn_mfma_f32_16x16x32_bf16(a, wd[ks], ya, 0, 0, 0);
        }
        const int f = w * 16 + lr;
#pragma unroll
        for (int r = 0; r < 4; ++r)
            Zb[(lg * 4 + r) * ZSTR + f] = (__bf16)ya[r];
    }

    float* outp = out + (size_t)row0 * SEQ * FD;

    // ---------------- 512-step recurrence ----------------
    for (int t = 0; t < SEQ; ++t) {
        __syncthreads();  // Z[cur] complete (h + x from previous iteration)

        const __bf16* Zc = &Zb[(t & 1) * (16 * ZSTR)];
        __bf16*       Zn = &Zb[((t + 1) & 1) * (16 * ZSTR)];

        // gates: 4 independent accumulator chains (i, f, g, o) for hidden j
        f32x4 acc[4];
#pragma unroll
        for (int nt = 0; nt < 4; ++nt)
            acc[nt] = f32x4{biasr[nt], biasr[nt], biasr[nt], biasr[nt]};

        // ks-outer: one A-frag (ds_read_b128) immediately feeds 4 gate chains
#pragma unroll
        for (int ks = 0; ks < 10; ++ks) {
            bf16x8 a = *(const bf16x8*)(&Zc[lr * ZSTR + ks * 32 + lg * 8]);
#pragma unroll
            for (int nt = 0; nt < 4; ++nt)
                acc[nt] = __builtin_amdgcn_mfma_f32_16x16x32_bf16(a, wg[nt][ks], acc[nt], 0, 0, 0);
        }

        // element-wise LSTM update; (m, j) owned by this lane for r = 0..3
#pragma unroll
        for (int r = 0; r < 4; ++r) {
            const int m = lg * 4 + r;
            const float ig = sigm(acc[0][r]);
            const float fg = sigm(acc[1][r]);
            const float gg = tanh_(acc[2][r]);
            const float og = sigm(acc[3][r]);
            const float cn = fg * creg[r] + ig * gg;
            creg[r] = cn;                         // fp32 master state stays in regs
            const float hn = og * tanh_(cn);
            Zn[m * ZSTR + 64 + j] = (__bf16)hn;   // h for next step
            CB[m * CSTR + j]      = (__bf16)cn;   // A-operand for dense
        }

        __syncthreads();  // CB ready (prev CB readers are past the top barrier)

        // y_t = c_new @ W_dense^T + b_dense  (waves 0..3; 8 MFMAs)
        if (w < 4) {
            f32x4 ya = {ybias, ybias, ybias, ybias};
#pragma unroll
            for (int ks = 0; ks < 8; ++ks) {
                bf16x8 av = *(const bf16x8*)(&CB[lr * CSTR + ks * 32 + lg * 8]);
                ya = __builtin_amdgcn_mfma_f32_16x16x32_bf16(av, wd[ks], ya, 0, 0, 0);
            }
            const int f = w * 16 + lr;
#pragma unroll
            for (int r = 0; r < 4; ++r) {
                const int m = lg * 4 + r;
                outp[(size_t)m * SEQ * FD + (size_t)t * FD + f] = ya[r]; // fp32 output
                Zn[m * ZSTR + f] = (__bf16)ya[r];                        // x for next step
            }
        }
    }
}

extern "C" void kernel_launch(void* const* d_in, const int* in_sizes, int n_in,
                              void* d_out, int out_size, void* d_ws, size_t ws_size,
                              hipStream_t stream) {
    (void)in_sizes; (void)n_in; (void)d_ws; (void)ws_size; (void)out_size;
    // setup_inputs order: x(0, unused), h0(1), c0(2), W_ih(3), W_hh(4),
    //                     b_ih(5), b_hh(6), W_dense(7), b_dense(8), seq_len(9)
    const float* h0      = (const float*)d_in[1];
    const float* c0      = (const float*)d_in[2];
    const float* W_ih    = (const float*)d_in[3];
    const float* W_hh    = (const float*)d_in[4];
    const float* b_ih    = (const float*)d_in[5];
    const float* b_hh    = (const float*)d_in[6];
    const float* W_dense = (const float*)d_in[7];
    const float* b_dense = (const float*)d_in[8];

    lstm_persist<<<128, 1024, 0, stream>>>(h0, c0, W_ih, W_hh, b_ih, b_hh,
                                           W_dense, b_dense, (float*)d_out);
}

// Round 3
// 3962.253 us; speedup vs baseline: 1.9576x; 1.8837x over previous
//
#include <hip/hip_runtime.h>
#include <stdint.h>

// Problem constants: B=2048, S=512, F=64, H=256
#define SEQ   512
#define FD    64
#define HD    256
#define ZSTR  324            // bf16 elems per Z row; 162 words % 8 == 2 -> 8/bank floor on b128
#define CSTR  260            // 130 words % 8 == 2

// Weight layout in d_ws (prep kernel writes, main kernel reads):
// 128 gate half-columns (hc): hc = (wave w, idx 0..15), idx -> (s=2w+(idx>>3), nt=(idx>>1)&3, h=idx&1).
// Each hc = 5 chunks of K=32; chunk = 64 lanes x 16B in exact B-fragment order:
//   lane l holds W[n = nt*256+s*16+(l&15)][k = h*160 + c*32 + (l>>4)*8 + e], e=0..7.
// Classes per wave: w<4: idx<4 REG, 4..6 LDS, 7..15 STREAM(9); w>=4: idx<6 REG, 6..8 LDS, 9..15 STREAM(7).
// Slots: REG 0..39, LDS 40..63, STREAM 64..127. Dense W after at byte 655360 (4 cols x 8 chunks x 1024B).
#define HC_ELEMS 2560        // 5120 bytes
#define WS_DENSE_ELEM (128 * HC_ELEMS)

typedef __attribute__((ext_vector_type(8))) __bf16 bf16x8;
typedef __attribute__((ext_vector_type(4))) float  f32x4;

__device__ __forceinline__ int hc_slot(int w, int idx) {
    const int R = (w < 4) ? 4 : 6;
    if (idx < R)     return (w < 4 ? w * 4 : 16 + (w - 4) * 6) + idx;
    if (idx < R + 3) return 40 + w * 3 + (idx - R);
    return 64 + (w < 4 ? w * 9 : 36 + (w - 4) * 7) + (idx - R - 3);
}

__device__ __forceinline__ float sigm(float x) {
    return __builtin_amdgcn_rcpf(1.0f + __expf(-x));
}
__device__ __forceinline__ float tanh_(float x) {
    return 2.0f * __builtin_amdgcn_rcpf(1.0f + __expf(-2.0f * x)) - 1.0f;
}

// ---------------- prep: fp32 weights -> bf16 fragments in ws ----------------
__global__ __launch_bounds__(64) void prep_weights(
    const float* __restrict__ W_ih, const float* __restrict__ W_hh,
    const float* __restrict__ W_dense, __bf16* __restrict__ wsb)
{
    const int b = blockIdx.x, l = threadIdx.x, lr = l & 15, lg = l >> 4;
    if (b < 128) {
        const int w = b >> 4, idx = b & 15;
        const int s = 2 * w + (idx >> 3), nt = (idx >> 1) & 3, h = idx & 1;
        const int n = nt * 256 + s * 16 + lr;
        const int slot = hc_slot(w, idx);
        for (int c = 0; c < 5; ++c) {
            const int k0 = h * 160 + c * 32 + lg * 8;
            const float* src = (k0 < 64) ? (W_ih + n * 64 + k0)
                                         : (W_hh + n * 256 + (k0 - 64));
            bf16x8 v;
            for (int e = 0; e < 8; ++e) v[e] = (__bf16)src[e];
            *(bf16x8*)(wsb + (size_t)slot * HC_ELEMS + c * 512 + l * 8) = v;
        }
    } else {
        const int d = b - 128;
        const int f = d * 16 + lr;
        for (int c = 0; c < 8; ++c) {
            const float* src = W_dense + f * 256 + c * 32 + lg * 8;
            bf16x8 v;
            for (int e = 0; e < 8; ++e) v[e] = (__bf16)src[e];
            *(bf16x8*)(wsb + WS_DENSE_ELEM + d * 4096 + c * 512 + l * 8) = v;
        }
    }
}

// ---------------- main persistent LSTM kernel ----------------
// 128 blocks x 512 threads (8 waves, 2/SIMD, VGPR cap 256). M=16 rows/block.
// Wave w owns j-slices {2w, 2w+1} (all 4 gates). Weights: REG + LDS-resident + L2-streamed.

template<int R, bool DENSE>
__device__ __forceinline__ void run_loop(
    bf16x8 (&wall)[30], const __bf16* __restrict__ wsb,
    const __bf16* __restrict__ WLDS, __bf16* __restrict__ Zb, __bf16* __restrict__ CBb,
    float (&creg)[2][4], const float (&biasv)[2][4], float ybias,
    float* __restrict__ outp, int w, int lr, int lg, int l)
{
    constexpr int NS = 16 - R - 3;    // stream hc count: 9 (w<4) or 7
    const __bf16* wstr_base = wsb +
        (size_t)(64 + (w < 4 ? w * 9 : 36 + (w - 4) * 7)) * HC_ELEMS + l * 8;
    const __bf16* wlds_base = WLDS + (size_t)(w * 3) * HC_ELEMS + l * 8;

    for (int t = 0; t < SEQ; ++t) {
        __syncthreads();   // barrier 1: Z[cur] (h + x) complete

        const __bf16* Zc = Zb + (t & 1) * (16 * ZSTR);
        __bf16*       Zn = Zb + ((t + 1) & 1) * (16 * ZSTR);

        // anti-LICM: launder the stream pointer so loop-invariant loads
        // are not hoisted out of the t-loop (which would spill everything).
        const __bf16* wstr = wstr_base;
        asm volatile("" : "+v"(wstr));

        bf16x8 sb0[5], sb1[5];
#define LOADSTR(BUF, I) { _Pragma("unroll") \
        for (int c = 0; c < 5; ++c) BUF[c] = *(const bf16x8*)(wstr + (I) * HC_ELEMS + c * 512); }
        LOADSTR(sb0, 0)
        LOADSTR(sb1, 1)

        // A-fragments: lane holds Z[lr][k = ks*32 + lg*8 + e]
        bf16x8 a[10];
#pragma unroll
        for (int ks = 0; ks < 10; ++ks)
            a[ks] = *(const bf16x8*)(&Zc[lr * ZSTR + ks * 32 + lg * 8]);

        f32x4 acc[4];
        int scnt = 0;
#pragma unroll
        for (int idx = 0; idx < 16; ++idx) {
            const int p = idx >> 3, nt = (idx >> 1) & 3, h = idx & 1;
            const float bb = biasv[p][nt];
            f32x4 cc = (h == 0) ? f32x4{bb, bb, bb, bb} : acc[nt];

#define MFMA5(SRC) { _Pragma("unroll") \
            for (int c = 0; c < 5; ++c) \
                cc = __builtin_amdgcn_mfma_f32_16x16x32_bf16(a[h * 5 + c], SRC, cc, 0, 0, 0); }

            if (idx < R) {
                MFMA5(wall[idx * 5 + c])
            } else if (idx < R + 3) {
                bf16x8 ld[5];
#pragma unroll
                for (int c = 0; c < 5; ++c)
                    ld[c] = *(const bf16x8*)(wlds_base + (idx - R) * HC_ELEMS + c * 512);
                MFMA5(ld[c])
            } else {
                if (scnt & 1) {
                    MFMA5(sb1[c])
                    if (scnt + 2 < NS) LOADSTR(sb1, scnt + 2)
                } else {
                    MFMA5(sb0[c])
                    if (scnt + 2 < NS) LOADSTR(sb0, scnt + 2)
                }
                ++scnt;
            }
            acc[nt] = cc;

            if ((idx & 7) == 7) {
                // element-wise LSTM update for slice p
                const int jj = (2 * w + p) * 16 + lr;
#pragma unroll
                for (int r = 0; r < 4; ++r) {
                    const int m = lg * 4 + r;
                    const float ig = sigm(acc[0][r]);
                    const float fg = sigm(acc[1][r]);
                    const float gg = tanh_(acc[2][r]);
                    const float og = sigm(acc[3][r]);
                    const float cn = fg * creg[p][r] + ig * gg;
                    creg[p][r] = cn;
                    const float hn = og * tanh_(cn);
                    Zn[m * ZSTR + 64 + jj] = (__bf16)hn;
                    CBb[m * CSTR + jj]     = (__bf16)cn;
                }
            }
        }

        __syncthreads();   // barrier 2: CB ready

        if (DENSE) {
            // y_t = c_new @ W_dense^T + b_dense (waves 0..3, col f in [16w,16w+16))
            f32x4 ya = {ybias, ybias, ybias, ybias};
#pragma unroll
            for (int c = 0; c < 8; ++c) {
                bf16x8 acb = *(const bf16x8*)(&CBb[lr * CSTR + c * 32 + lg * 8]);
                ya = __builtin_amdgcn_mfma_f32_16x16x32_bf16(acb, wall[20 + c], ya, 0, 0, 0);
            }
            const int f = w * 16 + lr;
#pragma unroll
            for (int r = 0; r < 4; ++r) {
                const int m = lg * 4 + r;
                outp[(size_t)m * (SEQ * FD) + t * FD + f] = ya[r];  // fp32 output
                Zn[m * ZSTR + f] = (__bf16)ya[r];                   // x for next step
            }
        }
    }
#undef MFMA5
#undef LOADSTR
}

__global__ __launch_bounds__(512, 2) void lstm_persist(
    const float* __restrict__ h0, const float* __restrict__ c0,
    const float* __restrict__ b_ih, const float* __restrict__ b_hh,
    const float* __restrict__ b_dense, const __bf16* __restrict__ wsb,
    float* __restrict__ out)
{
    __shared__ __align__(16) __bf16 WLDS[24 * HC_ELEMS];   // 122,880 B
    __shared__ __align__(16) __bf16 Zb[2 * 16 * ZSTR];     //  20,736 B
    __shared__ __align__(16) __bf16 CBb[16 * CSTR];        //   8,320 B

    const int tid = threadIdx.x;
    const int w   = tid >> 6;
    const int l   = tid & 63;
    const int lr  = l & 15;
    const int lg  = l >> 4;
    const int row0 = blockIdx.x * 16;
    const int R = (w < 4) ? 4 : 6;

    // ---- register-resident weights (REG class + dense on waves 0..3) ----
    bf16x8 wall[30];
    if (w < 4) {
#pragma unroll
        for (int i = 0; i < 4; ++i)
#pragma unroll
            for (int c = 0; c < 5; ++c)
                wall[i * 5 + c] = *(const bf16x8*)(wsb + (size_t)hc_slot(w, i) * HC_ELEMS + c * 512 + l * 8);
#pragma unroll
        for (int c = 0; c < 8; ++c)
            wall[20 + c] = *(const bf16x8*)(wsb + WS_DENSE_ELEM + w * 4096 + c * 512 + l * 8);
    } else {
#pragma unroll
        for (int i = 0; i < 6; ++i)
#pragma unroll
            for (int c = 0; c < 5; ++c)
                wall[i * 5 + c] = *(const bf16x8*)(wsb + (size_t)hc_slot(w, i) * HC_ELEMS + c * 512 + l * 8);
    }

    // ---- LDS-resident weights: each wave loads its 3 hc (one-time) ----
#pragma unroll
    for (int i = 0; i < 3; ++i)
#pragma unroll
        for (int c = 0; c < 5; ++c)
            *(bf16x8*)(WLDS + (size_t)(w * 3 + i) * HC_ELEMS + c * 512 + l * 8) =
                *(const bf16x8*)(wsb + (size_t)hc_slot(w, R + i) * HC_ELEMS + c * 512 + l * 8);

    // ---- biases, initial state ----
    float biasv[2][4];
    float creg[2][4];
#pragma unroll
    for (int p = 0; p < 2; ++p) {
        const int jj = (2 * w + p) * 16 + lr;
#pragma unroll
        for (int nt = 0; nt < 4; ++nt) {
            const int n = nt * 256 + jj;
            biasv[p][nt] = b_ih[n] + b_hh[n];
        }
#pragma unroll
        for (int r = 0; r < 4; ++r)
            creg[p][r] = c0[(size_t)(row0 + lg * 4 + r) * HD + jj];
    }
    float ybias = (w < 4) ? b_dense[w * 16 + lr] : 0.0f;

    // ---- stage h0 into Z0 h-part (512 threads x 8 elems) ----
    {
        const int e0 = tid * 8;
        const int m  = e0 >> 8;
        const int jj = e0 & 255;
        const float4 h1 = *(const float4*)(h0 + (size_t)(row0 + m) * HD + jj);
        const float4 h2 = *(const float4*)(h0 + (size_t)(row0 + m) * HD + jj + 4);
        __bf16* zp = &Zb[m * ZSTR + 64 + jj];
        zp[0] = (__bf16)h1.x; zp[1] = (__bf16)h1.y; zp[2] = (__bf16)h1.z; zp[3] = (__bf16)h1.w;
        zp[4] = (__bf16)h2.x; zp[5] = (__bf16)h2.y; zp[6] = (__bf16)h2.z; zp[7] = (__bf16)h2.w;
    }
    __syncthreads();

    // ---- x_0 = dense(h0) -> Z0 x-part ----
    if (w < 4) {
        f32x4 ya = {ybias, ybias, ybias, ybias};
#pragma unroll
        for (int c = 0; c < 8; ++c) {
            bf16x8 av = *(const bf16x8*)(&Zb[lr * ZSTR + 64 + c * 32 + lg * 8]);
            ya = __builtin_amdgcn_mfma_f32_16x16x32_bf16(av, wall[20 + c], ya, 0, 0, 0);
        }
#pragma unroll
        for (int r = 0; r < 4; ++r)
            Zb[(lg * 4 + r) * ZSTR + w * 16 + lr] = (__bf16)ya[r];
    }

    float* outp = out + (size_t)row0 * SEQ * FD;

    if (w < 4) run_loop<4, true >(wall, wsb, WLDS, Zb, CBb, creg, biasv, ybias, outp, w, lr, lg, l);
    else       run_loop<6, false>(wall, wsb, WLDS, Zb, CBb, creg, biasv, ybias, outp, w, lr, lg, l);
}

extern "C" void kernel_launch(void* const* d_in, const int* in_sizes, int n_in,
                              void* d_out, int out_size, void* d_ws, size_t ws_size,
                              hipStream_t stream) {
    (void)in_sizes; (void)n_in; (void)ws_size; (void)out_size;
    const float* h0      = (const float*)d_in[1];
    const float* c0      = (const float*)d_in[2];
    const float* W_ih    = (const float*)d_in[3];
    const float* W_hh    = (const float*)d_in[4];
    const float* b_ih    = (const float*)d_in[5];
    const float* b_hh    = (const float*)d_in[6];
    const float* W_dense = (const float*)d_in[7];
    const float* b_dense = (const float*)d_in[8];
    __bf16* wsb = (__bf16*)d_ws;    // uses 688,128 bytes of workspace

    prep_weights<<<132, 64, 0, stream>>>(W_ih, W_hh, W_dense, wsb);
    lstm_persist<<<128, 512, 0, stream>>>(h0, c0, b_ih, b_hh, b_dense, wsb, (float*)d_out);
}

// Round 5
// 3357.930 us; speedup vs baseline: 2.3098x; 1.1800x over previous
//
#include <hip/hip_runtime.h>
#include <stdint.h>

// Problem constants: B=2048, S=512, F=64, H=256
#define SEQ   512
#define FD    64
#define HD    256
#define ZSTR  324            // bf16 elems per Z row; 162 words % 8 == 2 -> 8/bank floor on b128
#define CSTR  260            // 130 words % 8 == 2

// Weight layout in d_ws (prep kernel writes, main kernel reads):
// 128 gate half-columns (hc): hc = (wave w, idx 0..15), idx -> (s=2w+(idx>>3), nt=(idx>>1)&3, h=idx&1).
// Each hc = 5 chunks of K=32; chunk = 64 lanes x 16B in exact B-fragment order:
//   lane l holds W[n = nt*256+s*16+(l&15)][k = h*160 + c*32 + (l>>4)*8 + e], e=0..7.
// Classes per wave: w<4: idx<3 REG, 3..5 LDS, 6..15 STREAM(10)
//                   w>=4: idx<5 REG, 5..7 LDS, 8..15 STREAM(8)
// Slots: REG 0..31, LDS 32..55, STREAM 56..127. Dense W at WS_DENSE_ELEM (4 x 8 chunks).
#define HC_ELEMS 2560        // 5120 bytes
#define WS_DENSE_ELEM (128 * HC_ELEMS)

typedef __attribute__((ext_vector_type(8))) __bf16 bf16x8;
typedef __attribute__((ext_vector_type(4))) float  f32x4;

__device__ __forceinline__ int hc_slot(int w, int idx) {
    const int R = (w < 4) ? 3 : 5;
    if (idx < R)     return (w < 4 ? w * 3 : 12 + (w - 4) * 5) + idx;
    if (idx < R + 3) return 32 + w * 3 + (idx - R);
    return 56 + (w < 4 ? w * 10 : 40 + (w - 4) * 8) + (idx - R - 3);
}

__device__ __forceinline__ float sigm(float x) {
    return __builtin_amdgcn_rcpf(1.0f + __expf(-x));
}
__device__ __forceinline__ float tanh_(float x) {
    return 2.0f * __builtin_amdgcn_rcpf(1.0f + __expf(-2.0f * x)) - 1.0f;
}

// ---------------- prep: fp32 weights -> bf16 fragments in ws ----------------
__global__ __launch_bounds__(64) void prep_weights(
    const float* __restrict__ W_ih, const float* __restrict__ W_hh,
    const float* __restrict__ W_dense, __bf16* __restrict__ wsb)
{
    const int b = blockIdx.x, l = threadIdx.x, lr = l & 15, lg = l >> 4;
    if (b < 128) {
        const int w = b >> 4, idx = b & 15;
        const int s = 2 * w + (idx >> 3), nt = (idx >> 1) & 3, h = idx & 1;
        const int n = nt * 256 + s * 16 + lr;
        const int slot = hc_slot(w, idx);
        for (int c = 0; c < 5; ++c) {
            const int k0 = h * 160 + c * 32 + lg * 8;
            const float* src = (k0 < 64) ? (W_ih + n * 64 + k0)
                                         : (W_hh + n * 256 + (k0 - 64));
            bf16x8 v;
            for (int e = 0; e < 8; ++e) v[e] = (__bf16)src[e];
            *(bf16x8*)(wsb + (size_t)slot * HC_ELEMS + c * 512 + l * 8) = v;
        }
    } else {
        const int d = b - 128;
        const int f = d * 16 + lr;
        for (int c = 0; c < 8; ++c) {
            const float* src = W_dense + f * 256 + c * 32 + lg * 8;
            bf16x8 v;
            for (int e = 0; e < 8; ++e) v[e] = (__bf16)src[e];
            *(bf16x8*)(wsb + WS_DENSE_ELEM + d * 4096 + c * 512 + l * 8) = v;
        }
    }
}

// ---------------- main persistent LSTM kernel ----------------
// 128 blocks x 512 threads (8 waves). LDS (152 KB) forces 1 block/CU = 2 waves/SIMD;
// amdgpu_waves_per_eu(2,2) pins the allocator's occupancy target there -> 256 VGPR budget.
// wall[] layout (all indices compile-time): gate chunks [0, 5R); dense (w<4 only) [5R, 5R+8).
// Worst case w>=4: 25 chunks. w<4: 15+8=23 chunks.  (R4's NaN was wall[25+c] overrunning wall[30].)

template<int R, bool DENSE>
__device__ __forceinline__ void run_loop(
    bf16x8 (&wall)[25], const __bf16* __restrict__ wsb,
    const __bf16* __restrict__ WLDS, __bf16* __restrict__ Zb, __bf16* __restrict__ CBb,
    float (&creg)[2][4], const float (&biasv)[2][4], float ybias,
    float* __restrict__ outp, int w, int lr, int lg, int l)
{
    constexpr int NS = 16 - R - 3;    // stream hc count: 10 (w<4) or 8
    const __bf16* wstr_base = wsb +
        (size_t)(56 + (w < 4 ? w * 10 : 40 + (w - 4) * 8)) * HC_ELEMS + l * 8;
    const __bf16* wlds_base = WLDS + (size_t)(w * 3) * HC_ELEMS + l * 8;

    for (int t = 0; t < SEQ; ++t) {
        __syncthreads();   // barrier 1: Z[cur] (h + x) complete

        const __bf16* Zc = Zb + (t & 1) * (16 * ZSTR);
        __bf16*       Zn = Zb + ((t + 1) & 1) * (16 * ZSTR);

        // anti-LICM: launder the stream pointer so loop-invariant loads
        // are not hoisted out of the t-loop (which would spill everything).
        const __bf16* wstr = wstr_base;
        asm volatile("" : "+v"(wstr));

        bf16x8 sb0[5], sb1[5];
#define LOADSTR(BUF, I) { _Pragma("unroll") \
        for (int c = 0; c < 5; ++c) BUF[c] = *(const bf16x8*)(wstr + (I) * HC_ELEMS + c * 512); }
        LOADSTR(sb0, 0)
        LOADSTR(sb1, 1)

        // A-fragments: lane holds Z[lr][k = ks*32 + lg*8 + e]
        bf16x8 a[10];
#pragma unroll
        for (int ks = 0; ks < 10; ++ks)
            a[ks] = *(const bf16x8*)(&Zc[lr * ZSTR + ks * 32 + lg * 8]);

        f32x4 acc[4];
        int scnt = 0;
#pragma unroll
        for (int idx = 0; idx < 16; ++idx) {
            const int p = idx >> 3, nt = (idx >> 1) & 3, h = idx & 1;
            const float bb = biasv[p][nt];
            f32x4 cc = (h == 0) ? f32x4{bb, bb, bb, bb} : acc[nt];

#define MFMA5(SRC) { _Pragma("unroll") \
            for (int c = 0; c < 5; ++c) \
                cc = __builtin_amdgcn_mfma_f32_16x16x32_bf16(a[h * 5 + c], SRC, cc, 0, 0, 0); }

            if (idx < R) {
                MFMA5(wall[idx * 5 + c])
            } else if (idx < R + 3) {
                bf16x8 ld[5];
#pragma unroll
                for (int c = 0; c < 5; ++c)
                    ld[c] = *(const bf16x8*)(wlds_base + (idx - R) * HC_ELEMS + c * 512);
                MFMA5(ld[c])
            } else {
                if (scnt & 1) {
                    MFMA5(sb1[c])
                    if (scnt + 2 < NS) LOADSTR(sb1, scnt + 2)
                } else {
                    MFMA5(sb0[c])
                    if (scnt + 2 < NS) LOADSTR(sb0, scnt + 2)
                }
                ++scnt;
            }
            acc[nt] = cc;

            if ((idx & 7) == 7) {
                // element-wise LSTM update for slice p
                const int jj = (2 * w + p) * 16 + lr;
#pragma unroll
                for (int r = 0; r < 4; ++r) {
                    const int m = lg * 4 + r;
                    const float ig = sigm(acc[0][r]);
                    const float fg = sigm(acc[1][r]);
                    const float gg = tanh_(acc[2][r]);
                    const float og = sigm(acc[3][r]);
                    const float cn = fg * creg[p][r] + ig * gg;
                    creg[p][r] = cn;
                    const float hn = og * tanh_(cn);
                    Zn[m * ZSTR + 64 + jj] = (__bf16)hn;
                    CBb[m * CSTR + jj]     = (__bf16)cn;
                }
            }
        }

        __syncthreads();   // barrier 2: CB ready

        if (DENSE) {
            // y_t = c_new @ W_dense^T + b_dense (waves 0..3, col f in [16w,16w+16))
            f32x4 ya = {ybias, ybias, ybias, ybias};
#pragma unroll
            for (int c = 0; c < 8; ++c) {
                bf16x8 acb = *(const bf16x8*)(&CBb[lr * CSTR + c * 32 + lg * 8]);
                ya = __builtin_amdgcn_mfma_f32_16x16x32_bf16(acb, wall[R * 5 + c], ya, 0, 0, 0);
            }
            const int f = w * 16 + lr;
#pragma unroll
            for (int r = 0; r < 4; ++r) {
                const int m = lg * 4 + r;
                outp[(size_t)m * (SEQ * FD) + t * FD + f] = ya[r];  // fp32 output
                Zn[m * ZSTR + f] = (__bf16)ya[r];                   // x for next step
            }
        }
    }
#undef MFMA5
#undef LOADSTR
}

__global__ __launch_bounds__(512) __attribute__((amdgpu_waves_per_eu(2, 2)))
void lstm_persist(
    const float* __restrict__ h0, const float* __restrict__ c0,
    const float* __restrict__ b_ih, const float* __restrict__ b_hh,
    const float* __restrict__ b_dense, const __bf16* __restrict__ wsb,
    float* __restrict__ out)
{
    __shared__ __align__(16) __bf16 WLDS[24 * HC_ELEMS];   // 122,880 B
    __shared__ __align__(16) __bf16 Zb[2 * 16 * ZSTR];     //  20,736 B
    __shared__ __align__(16) __bf16 CBb[16 * CSTR];        //   8,320 B

    const int tid = threadIdx.x;
    const int w   = tid >> 6;
    const int l   = tid & 63;
    const int lr  = l & 15;
    const int lg  = l >> 4;
    const int row0 = blockIdx.x * 16;
    const int R = (w < 4) ? 3 : 5;

    // ---- register-resident weights (REG class + dense on waves 0..3) ----
    bf16x8 wall[25];
    if (w < 4) {
#pragma unroll
        for (int i = 0; i < 3; ++i)
#pragma unroll
            for (int c = 0; c < 5; ++c)
                wall[i * 5 + c] = *(const bf16x8*)(wsb + (size_t)hc_slot(w, i) * HC_ELEMS + c * 512 + l * 8);
#pragma unroll
        for (int c = 0; c < 8; ++c)   // dense chunks at [15, 23)
            wall[15 + c] = *(const bf16x8*)(wsb + WS_DENSE_ELEM + w * 4096 + c * 512 + l * 8);
    } else {
#pragma unroll
        for (int i = 0; i < 5; ++i)
#pragma unroll
            for (int c = 0; c < 5; ++c)
                wall[i * 5 + c] = *(const bf16x8*)(wsb + (size_t)hc_slot(w, i) * HC_ELEMS + c * 512 + l * 8);
    }

    // ---- LDS-resident weights: each wave stages its 3 hc (one-time) ----
#pragma unroll
    for (int i = 0; i < 3; ++i)
#pragma unroll
        for (int c = 0; c < 5; ++c)
            *(bf16x8*)(WLDS + (size_t)(w * 3 + i) * HC_ELEMS + c * 512 + l * 8) =
                *(const bf16x8*)(wsb + (size_t)hc_slot(w, R + i) * HC_ELEMS + c * 512 + l * 8);

    // ---- biases, initial state ----
    float biasv[2][4];
    float creg[2][4];
#pragma unroll
    for (int p = 0; p < 2; ++p) {
        const int jj = (2 * w + p) * 16 + lr;
#pragma unroll
        for (int nt = 0; nt < 4; ++nt) {
            const int n = nt * 256 + jj;
            biasv[p][nt] = b_ih[n] + b_hh[n];
        }
#pragma unroll
        for (int r = 0; r < 4; ++r)
            creg[p][r] = c0[(size_t)(row0 + lg * 4 + r) * HD + jj];
    }
    float ybias = (w < 4) ? b_dense[w * 16 + lr] : 0.0f;

    // ---- stage h0 into Z0 h-part (512 threads x 8 elems) ----
    {
        const int e0 = tid * 8;
        const int m  = e0 >> 8;
        const int jj = e0 & 255;
        const float4 h1 = *(const float4*)(h0 + (size_t)(row0 + m) * HD + jj);
        const float4 h2 = *(const float4*)(h0 + (size_t)(row0 + m) * HD + jj + 4);
        __bf16* zp = &Zb[m * ZSTR + 64 + jj];
        zp[0] = (__bf16)h1.x; zp[1] = (__bf16)h1.y; zp[2] = (__bf16)h1.z; zp[3] = (__bf16)h1.w;
        zp[4] = (__bf16)h2.x; zp[5] = (__bf16)h2.y; zp[6] = (__bf16)h2.z; zp[7] = (__bf16)h2.w;
    }
    __syncthreads();

    // ---- x_0 = dense(h0) -> Z0 x-part ----
    if (w < 4) {
        f32x4 ya = {ybias, ybias, ybias, ybias};
#pragma unroll
        for (int c = 0; c < 8; ++c) {
            bf16x8 av = *(const bf16x8*)(&Zb[lr * ZSTR + 64 + c * 32 + lg * 8]);
            ya = __builtin_amdgcn_mfma_f32_16x16x32_bf16(av, wall[15 + c], ya, 0, 0, 0);
        }
#pragma unroll
        for (int r = 0; r < 4; ++r)
            Zb[(lg * 4 + r) * ZSTR + w * 16 + lr] = (__bf16)ya[r];
    }

    float* outp = out + (size_t)row0 * SEQ * FD;

    if (w < 4) run_loop<3, true >(wall, wsb, WLDS, Zb, CBb, creg, biasv, ybias, outp, w, lr, lg, l);
    else       run_loop<5, false>(wall, wsb, WLDS, Zb, CBb, creg, biasv, ybias, outp, w, lr, lg, l);
}

extern "C" void kernel_launch(void* const* d_in, const int* in_sizes, int n_in,
                              void* d_out, int out_size, void* d_ws, size_t ws_size,
                              hipStream_t stream) {
    (void)in_sizes; (void)n_in; (void)ws_size; (void)out_size;
    const float* h0      = (const float*)d_in[1];
    const float* c0      = (const float*)d_in[2];
    const float* W_ih    = (const float*)d_in[3];
    const float* W_hh    = (const float*)d_in[4];
    const float* b_ih    = (const float*)d_in[5];
    const float* b_hh    = (const float*)d_in[6];
    const float* W_dense = (const float*)d_in[7];
    const float* b_dense = (const float*)d_in[8];
    __bf16* wsb = (__bf16*)d_ws;    // uses 688,128 bytes of workspace

    prep_weights<<<132, 64, 0, stream>>>(W_ih, W_hh, W_dense, wsb);
    lstm_persist<<<128, 512, 0, stream>>>(h0, c0, b_ih, b_hh, b_dense, wsb, (float*)d_out);
}